// Round 9
// baseline (619.109 us; speedup 1.0000x reference)
//
#include <hip/hip_runtime.h>

// ---------------------------------------------------------------------------
// HeteroGAT (2 layers, 3 relations) on MI355X. 6 dispatches/call.
//   front1: bucket_scatter (ECH=4096 chunks) + prep (WDA/Wt/bsum) fused
//   front2: bucket_build + conv_ed (x->fp16 + layer-1 ed GEMVs) fused
//   gemm3:  all 3 relations' hs = X@Wsrc (fp16 MFMA) + fused es, one dispatch
//   agg_fused: per layer, dual-relation (paper dst) + single-relation
//           (author dst) aggregates in ONE dispatch (block-range split).
//   Gather: dual-edge half-wave layout on BOTH paths (proven on CH=64 in R7):
//   half=lane>>5 selects edge j+half; CH=128: cl=lane&31 owns channels
//   4cl..4cl+3 (h4=8B loads); CH=64: cl owns (2cl,2cl+1) (h2 loads).
//   Direct-exp softmax + one-block-ahead (s,es) prefetch. shfl sources
//   span <=8 lanes -> 0 LDS bank conflicts (measured R7/R8).
// ---------------------------------------------------------------------------

#define LEAKY(x) ((x) > 0.f ? (x) : 0.2f * (x))
#define ECH 4096
#define NBMAX 784

typedef _Float16 h8 __attribute__((ext_vector_type(8)));
typedef _Float16 h4 __attribute__((ext_vector_type(4)));
typedef _Float16 h2 __attribute__((ext_vector_type(2)));
typedef float f4 __attribute__((ext_vector_type(4)));

// ---------------- front1: bucket_scatter chunks + prep ----------------
__launch_bounds__(256)
__global__ void front1(
    const int* __restrict__ s0, const int* __restrict__ d0, int E0,
    int* __restrict__ bc0, int* __restrict__ bt0, int C0, int NB0, int c0,
    const int* __restrict__ s1, const int* __restrict__ d1, int E1,
    int* __restrict__ bc1, int* __restrict__ bt1, int C1, int NB1, int c1,
    const int* __restrict__ s2, const int* __restrict__ d2, int E2,
    int* __restrict__ bc2, int* __restrict__ bt2, int C2, int NB2,
    const float* __restrict__ Wdst1, const float* __restrict__ adst1,
    const float* __restrict__ Wdst2, const float* __restrict__ adst2,
    const float* __restrict__ Wsrc1, const float* __restrict__ Wsrc2,
    const float* __restrict__ b1, const float* __restrict__ b2,
    float* __restrict__ WDA, _Float16* __restrict__ Wt,
    float* __restrict__ bsum, int S) {
    __shared__ int lcnt[NBMAX], lbase[NBMAX];
    int blk = blockIdx.x;
    int t = threadIdx.x;
    if (blk < S) {
        int ch = blk;
        const int* src; const int* dst; int* bc; int* bt; int cap, NB, E;
        if (ch < c0)            { src = s0; dst = d0; bc = bc0; bt = bt0; cap = C0; NB = NB0; E = E0; }
        else if (ch < c0 + c1)  { ch -= c0; src = s1; dst = d1; bc = bc1; bt = bt1; cap = C1; NB = NB1; E = E1; }
        else                    { ch -= c0 + c1; src = s2; dst = d2; bc = bc2; bt = bt2; cap = C2; NB = NB2; E = E2; }
        int ebeg = ch * ECH;
        int eend = ebeg + ECH < E ? ebeg + ECH : E;

        for (int b = t; b < NB; b += 256) lcnt[b] = 0;
        __syncthreads();
        for (int i = ebeg + t; i < eend; i += 256) atomicAdd(&lcnt[dst[i] >> 7], 1);
        __syncthreads();
        for (int b = t; b < NB; b += 256) {
            int c = lcnt[b];
            lbase[b] = c ? atomicAdd(&bc[b], c) : 0;
            lcnt[b] = 0;
        }
        __syncthreads();
        for (int i = ebeg + t; i < eend; i += 256) {
            int d = dst[i], b = d >> 7;
            int p = lbase[b] + atomicAdd(&lcnt[b], 1);
            if (p < cap) bt[(size_t)b * cap + p] = src[i] | ((d & 127) << 20);
        }
    } else {
        int r = blk - S;
        if (r < 6) {
            const float* Wd; const float* ad; int Ncol, C;
            if (r < 3) { Wd = Wdst1 + r * 16384; ad = adst1 + r * 128; Ncol = 128; C = 32; }
            else       { Wd = Wdst2 + (r - 3) * 8192; ad = adst2 + (r - 3) * 64; Ncol = 64; C = 16; }
            for (int tt = t; tt < 512; tt += 256) {
                int f = tt >> 2, h = tt & 3;
                float s = 0.f;
                for (int c = 0; c < C; ++c) s += Wd[f * Ncol + h * C + c] * ad[h * C + c];
                WDA[r * 512 + f * 4 + h] = s;
            }
        } else if (r < 12) {
            int rr = r - 6;
            const float* W; _Float16* o; int BN;
            if (rr < 3) { W = Wsrc1 + rr * 16384; o = Wt + rr * 16384; BN = 128; }
            else        { W = Wsrc2 + (rr - 3) * 8192; o = Wt + 3 * 16384 + (rr - 3) * 8192; BN = 64; }
            for (int idx = t; idx < BN * 128; idx += 256) {
                int n = idx >> 7, k = idx & 127;
                o[idx] = (_Float16)W[k * BN + n];
            }
        } else {
            if (t < 128) bsum[t] = b1[t] + b1[128 + t];
            else if (t < 192) bsum[128 + (t - 128)] = b2[t - 128] + b2[64 + (t - 128)];
        }
    }
}

// ---------------- front2: bucket_build + conv_ed ----------------
__launch_bounds__(256)
__global__ void front2(
    const int* __restrict__ bt0, const int* __restrict__ bc0, int* __restrict__ ss0,
    int* __restrict__ beg0, int* __restrict__ end0, int NB0, int C0, int Nd0,
    const int* __restrict__ bt1, const int* __restrict__ bc1, int* __restrict__ ss1,
    int* __restrict__ beg1, int* __restrict__ end1, int NB1, int C1, int Nd1,
    const int* __restrict__ bt2, const int* __restrict__ bc2, int* __restrict__ ss2,
    int* __restrict__ beg2, int* __restrict__ end2, int NB2, int C2, int Nd2,
    int NBtot,
    const float* __restrict__ xp, const float* __restrict__ xa,
    int NP, int NA, _Float16* __restrict__ xph, _Float16* __restrict__ xah,
    const float* __restrict__ WDA,
    float* __restrict__ EDpp, float* __restrict__ EDap, float* __restrict__ EDpa) {
    __shared__ int hist[128], pre[129], cur[128];
    int blk = blockIdx.x;
    int tid = threadIdx.x;
    if (blk < NBtot) {
        int bb = blk;
        const int* bt; const int* bcp; int* ssp; int* bg; int* en; int cap, nd;
        if (bb < NB0)            { bt = bt0; bcp = bc0; ssp = ss0; bg = beg0; en = end0; cap = C0; nd = Nd0; }
        else if (bb < NB0 + NB1) { bb -= NB0; bt = bt1; bcp = bc1; ssp = ss1; bg = beg1; en = end1; cap = C1; nd = Nd1; }
        else                     { bb -= NB0 + NB1; bt = bt2; bcp = bc2; ssp = ss2; bg = beg2; en = end2; cap = C2; nd = Nd2; }
        int n = bcp[bb]; if (n > cap) n = cap;
        const int* btb = bt + (size_t)bb * cap;
        int ssbase = bb * cap;
        int dbase = bb << 7;

        if (tid < 128) hist[tid] = 0;
        __syncthreads();
        for (int i = tid; i < n; i += 256) atomicAdd(&hist[btb[i] >> 20], 1);
        __syncthreads();
        if (tid < 128) pre[tid + 1] = hist[tid];
        if (tid == 0) pre[0] = 0;
        __syncthreads();
        for (int off = 1; off < 128; off <<= 1) {
            int v = 0;
            if (tid < 128) {
                int i = tid + 1;
                v = pre[i] + ((i > off) ? pre[i - off] : 0);
            }
            __syncthreads();
            if (tid < 128) pre[tid + 1] = v;
            __syncthreads();
        }
        if (tid < 128) {
            int d = dbase + tid;
            if (d < nd) {
                int b_ = ssbase + pre[tid];
                bg[d] = b_;
                en[d] = b_ + hist[tid];
            }
            cur[tid] = 0;
        }
        __syncthreads();
        for (int i = tid; i < n; i += 256) {
            int v = btb[i];
            int dl = v >> 20;
            int p = atomicAdd(&cur[dl], 1);
            ssp[ssbase + pre[dl] + p] = v & 0xFFFFF;
        }
    } else {
        int wid = (blk - NBtot) * 4 + (tid >> 6);
        if (wid >= NP + NA) return;
        int lane = tid & 63;
        const float* x; _Float16* xh; const float4* W0; const float4* W1;
        float* e0p; float* e1p; int row;
        if (wid < NP) { row = wid; x = xp; xh = xph; W0 = (const float4*)WDA;
                        W1 = (const float4*)(WDA + 512); e0p = EDpp; e1p = EDap; }
        else { row = wid - NP; x = xa; xh = xah; W0 = (const float4*)(WDA + 1024);
               W1 = nullptr; e0p = EDpa; e1p = nullptr; }
        float2 xv = *(const float2*)(x + (size_t)row * 128 + lane * 2);
        h2 hv = {(_Float16)xv.x, (_Float16)xv.y};
        *(h2*)(xh + (size_t)row * 128 + lane * 2) = hv;
        float4 a0 = W0[lane * 2], a1 = W0[lane * 2 + 1];
        float4 p = make_float4(xv.x * a0.x + xv.y * a1.x, xv.x * a0.y + xv.y * a1.y,
                               xv.x * a0.z + xv.y * a1.z, xv.x * a0.w + xv.y * a1.w);
        float4 q = make_float4(0.f, 0.f, 0.f, 0.f);
        if (W1) {
            float4 b0 = W1[lane * 2], b1 = W1[lane * 2 + 1];
            q = make_float4(xv.x * b0.x + xv.y * b1.x, xv.x * b0.y + xv.y * b1.y,
                            xv.x * b0.z + xv.y * b1.z, xv.x * b0.w + xv.y * b1.w);
        }
#pragma unroll
        for (int off = 32; off; off >>= 1) {
            p.x += __shfl_xor(p.x, off); p.y += __shfl_xor(p.y, off);
            p.z += __shfl_xor(p.z, off); p.w += __shfl_xor(p.w, off);
            q.x += __shfl_xor(q.x, off); q.y += __shfl_xor(q.y, off);
            q.z += __shfl_xor(q.z, off); q.w += __shfl_xor(q.w, off);
        }
        if (lane == 0) {
            *(float4*)(e0p + (size_t)row * 4) = p;
            if (e1p) *(float4*)(e1p + (size_t)row * 4) = q;
        }
    }
}

// ---------------- fp16 MFMA GEMM x3 relations + fused es ----------------
template <int BN>
__launch_bounds__(256)
__global__ void gemm3(const _Float16* __restrict__ A0, int M0, const _Float16* __restrict__ W0,
                      const float* __restrict__ as0, _Float16* __restrict__ O0, float* __restrict__ es0,
                      const _Float16* __restrict__ A1, int M1, const _Float16* __restrict__ W1,
                      const float* __restrict__ as1, _Float16* __restrict__ O1, float* __restrict__ es1,
                      const _Float16* __restrict__ A2, int M2, const _Float16* __restrict__ W2,
                      const float* __restrict__ as2, _Float16* __restrict__ O2, float* __restrict__ es2,
                      int t0, int t1) {
    constexpr int NT = BN / 16;
    constexpr int LDA = 136;
    __shared__ _Float16 As[64 * LDA];
    __shared__ _Float16 Ws[BN * LDA];
    int b = blockIdx.x;
    const _Float16* A; const _Float16* Wt; const float* a_s; _Float16* Chs; float* es;
    int M, tile;
    if (b < t0)      { A = A0; M = M0; Wt = W0; a_s = as0; Chs = O0; es = es0; tile = b; }
    else if (b < t1) { A = A1; M = M1; Wt = W1; a_s = as1; Chs = O1; es = es1; tile = b - t0; }
    else             { A = A2; M = M2; Wt = W2; a_s = as2; Chs = O2; es = es2; tile = b - t1; }
    const int tid = threadIdx.x;
    const int wave = tid >> 6, lane = tid & 63;
    const int l15 = lane & 15, quad = lane >> 4;
    const int row0 = tile * 64;
    const int maxr = M - row0;

#pragma unroll
    for (int c = 0; c < 4; ++c) {
        int idx = c * 256 + tid;
        int row = idx >> 4, off = (idx & 15) * 8;
        h8 v = {};
        if (row < maxr) v = *(const h8*)(A + (size_t)(row0 + row) * 128 + off);
        *(h8*)(As + row * LDA + off) = v;
    }
#pragma unroll
    for (int c = 0; c < NT; ++c) {
        int idx = c * 256 + tid;
        int row = idx >> 4, off = (idx & 15) * 8;
        *(h8*)(Ws + row * LDA + off) = *(const h8*)(Wt + (size_t)row * 128 + off);
    }
    __syncthreads();

    f4 acc[NT];
#pragma unroll
    for (int nt = 0; nt < NT; ++nt) acc[nt] = {0.f, 0.f, 0.f, 0.f};

    const _Float16* ap = As + (wave * 16 + l15) * LDA + quad * 8;
#pragma unroll
    for (int k0 = 0; k0 < 128; k0 += 32) {
        h8 a = *(const h8*)(ap + k0);
#pragma unroll
        for (int nt = 0; nt < NT; ++nt) {
            h8 bb = *(const h8*)(Ws + (nt * 16 + l15) * LDA + k0 + quad * 8);
            acc[nt] = __builtin_amdgcn_mfma_f32_16x16x32_f16(a, bb, acc[nt], 0, 0, 0);
        }
    }

    float av[NT];
#pragma unroll
    for (int nt = 0; nt < NT; ++nt) av[nt] = a_s[nt * 16 + l15];
    constexpr int TPH = NT / 4;
#pragma unroll
    for (int r = 0; r < 4; ++r) {
        int row = wave * 16 + quad * 4 + r;
        bool ok = row < maxr;
        if (ok) {
            _Float16* outp = Chs + (size_t)(row0 + row) * BN + l15;
#pragma unroll
            for (int nt = 0; nt < NT; ++nt) outp[nt * 16] = (_Float16)acc[nt][r];
        }
        float p0 = 0.f, p1 = 0.f, p2 = 0.f, p3 = 0.f;
#pragma unroll
        for (int i = 0; i < TPH; ++i) {
            p0 += acc[0 * TPH + i][r] * av[0 * TPH + i];
            p1 += acc[1 * TPH + i][r] * av[1 * TPH + i];
            p2 += acc[2 * TPH + i][r] * av[2 * TPH + i];
            p3 += acc[3 * TPH + i][r] * av[3 * TPH + i];
        }
#pragma unroll
        for (int off = 1; off < 16; off <<= 1) {
            p0 += __shfl_xor(p0, off);
            p1 += __shfl_xor(p1, off);
            p2 += __shfl_xor(p2, off);
            p3 += __shfl_xor(p3, off);
        }
        if (ok && l15 < 4) {
            float pv = (l15 == 0) ? p0 : (l15 == 1) ? p1 : (l15 == 2) ? p2 : p3;
            es[(size_t)(row0 + row) * 4 + l15] = pv;
        }
    }
}

// ---------------- aggregation ----------------
// Direct-exp softmax; (s,es) prefetched one 16-edge block ahead.
// Dual-edge half-wave gather: half = lane>>5 picks edge j+half.
//   CH=128: cl=lane&31 owns channels 4cl..4cl+3 (h4 loads, 8B).
//   CH=64:  cl=lane&31 owns channels (2cl,2cl+1) (h2 loads).
// acc returned in racc[0..3] (CH=128) or racc[0..1] (CH=64), valid in all
// lanes after the xor-32 half merge.
template <int CH>
__device__ __forceinline__ void gat_gather(
    int b0, int e0, const int* __restrict__ ss, const _Float16* __restrict__ hs,
    const float* __restrict__ es, float edh, int lane, int h, int el,
    float* __restrict__ racc, float& rden) {
    const char* hsb = (const char*)hs;
    const char* esb = (const char*)es;
    const int half = lane >> 5;
    const int cl = lane & 31;
    float den = 0.f;
    int n = e0 - b0; if (n > 16) n = 16; if (n < 0) n = 0;
    int s = 0; float eraw = 0.f;
    if (el < n) {
        s = ss[b0 + el];
        eraw = *(const float*)(esb + ((unsigned)s * 16u + (unsigned)(h * 4)));
    }
    if constexpr (CH == 128) {
        const int hh = cl >> 3;                 // head of channels 4cl..4cl+3
        const unsigned lb = (unsigned)(cl * 8); // 4 ch x 2B
        float a0 = 0.f, a1 = 0.f, a2 = 0.f, a3 = 0.f;
        for (int base = b0; base < e0; base += 16) {
            int n2 = e0 - (base + 16); if (n2 > 16) n2 = 16;
            int sp = 0; float erawp = 0.f;
            if (el < n2) {
                sp = ss[base + 16 + el];
                erawp = *(const float*)(esb + ((unsigned)sp * 16u + (unsigned)(h * 4)));
            }
            float w = 0.f;
            if (el < n) {
                float e = eraw + edh;
                e = LEAKY(e);
                w = __expf(e);
            }
            // padded slots (>=n) carry s=0, w=0 -> harmless row-0 loads.
            for (int j = 0; j < n; j += 8) {
                int t0 = __shfl(s, j + half);
                int t1 = __shfl(s, j + 2 + half);
                int t2 = __shfl(s, j + 4 + half);
                int t3 = __shfl(s, j + 6 + half);
                float w0 = __shfl(w, (hh << 4) | (j + half));
                float w1 = __shfl(w, (hh << 4) | (j + 2 + half));
                float w2 = __shfl(w, (hh << 4) | (j + 4 + half));
                float w3 = __shfl(w, (hh << 4) | (j + 6 + half));
                h4 v0 = *(const h4*)(hsb + ((unsigned)t0 * 256u + lb));
                h4 v1 = *(const h4*)(hsb + ((unsigned)t1 * 256u + lb));
                h4 v2 = *(const h4*)(hsb + ((unsigned)t2 * 256u + lb));
                h4 v3 = *(const h4*)(hsb + ((unsigned)t3 * 256u + lb));
                a0 += w0 * (float)v0[0] + w1 * (float)v1[0] + w2 * (float)v2[0] + w3 * (float)v3[0];
                a1 += w0 * (float)v0[1] + w1 * (float)v1[1] + w2 * (float)v2[1] + w3 * (float)v3[1];
                a2 += w0 * (float)v0[2] + w1 * (float)v1[2] + w2 * (float)v2[2] + w3 * (float)v3[2];
                a3 += w0 * (float)v0[3] + w1 * (float)v1[3] + w2 * (float)v2[3] + w3 * (float)v3[3];
                den += w0 + w1 + w2 + w3;
            }
            s = sp; eraw = erawp; n = n2;
        }
        a0 += __shfl_xor(a0, 32);
        a1 += __shfl_xor(a1, 32);
        a2 += __shfl_xor(a2, 32);
        a3 += __shfl_xor(a3, 32);
        den += __shfl_xor(den, 32);
        racc[0] = a0; racc[1] = a1; racc[2] = a2; racc[3] = a3;
    } else {
        const int hh = cl >> 3;                 // head of channels 2cl,2cl+1
        const unsigned lb = (unsigned)(cl * 4);
        float a0 = 0.f, a1 = 0.f;
        for (int base = b0; base < e0; base += 16) {
            int n2 = e0 - (base + 16); if (n2 > 16) n2 = 16;
            int sp = 0; float erawp = 0.f;
            if (el < n2) {
                sp = ss[base + 16 + el];
                erawp = *(const float*)(esb + ((unsigned)sp * 16u + (unsigned)(h * 4)));
            }
            float w = 0.f;
            if (el < n) {
                float e = eraw + edh;
                e = LEAKY(e);
                w = __expf(e);
            }
            for (int j = 0; j < n; j += 8) {
                int t0 = __shfl(s, j + half);
                int t1 = __shfl(s, j + 2 + half);
                int t2 = __shfl(s, j + 4 + half);
                int t3 = __shfl(s, j + 6 + half);
                float w0 = __shfl(w, (hh << 4) | (j + half));
                float w1 = __shfl(w, (hh << 4) | (j + 2 + half));
                float w2 = __shfl(w, (hh << 4) | (j + 4 + half));
                float w3 = __shfl(w, (hh << 4) | (j + 6 + half));
                h2 v0 = *(const h2*)(hsb + ((unsigned)t0 * 128u + lb));
                h2 v1 = *(const h2*)(hsb + ((unsigned)t1 * 128u + lb));
                h2 v2 = *(const h2*)(hsb + ((unsigned)t2 * 128u + lb));
                h2 v3 = *(const h2*)(hsb + ((unsigned)t3 * 128u + lb));
                a0 += w0 * (float)v0[0] + w1 * (float)v1[0] + w2 * (float)v2[0] + w3 * (float)v3[0];
                a1 += w0 * (float)v0[1] + w1 * (float)v1[1] + w2 * (float)v2[1] + w3 * (float)v3[1];
                den += w0 + w1 + w2 + w3;
            }
            s = sp; eraw = erawp; n = n2;
        }
        a0 += __shfl_xor(a0, 32);
        a1 += __shfl_xor(a1, 32);
        den += __shfl_xor(den, 32);
        racc[0] = a0; racc[1] = a1;
    }
    rden = den;
}

// 4-channel ed reduce: lane owns channels 4cl..4cl+3 (replicated across
// halves); xor-reduce within each 32-lane half gives the full sum.
__device__ __forceinline__ void ed_reduce_write4(const float* __restrict__ o,
                                                 const float* __restrict__ wda,
                                                 float* __restrict__ edO,
                                                 int wid, int cl, int lane) {
    const float4* W = (const float4*)wda;
    float4 p = make_float4(0.f, 0.f, 0.f, 0.f);
#pragma unroll
    for (int i = 0; i < 4; ++i) {
        float4 wv = W[cl * 4 + i];
        p.x = fmaf(o[i], wv.x, p.x);
        p.y = fmaf(o[i], wv.y, p.y);
        p.z = fmaf(o[i], wv.z, p.z);
        p.w = fmaf(o[i], wv.w, p.w);
    }
#pragma unroll
    for (int off = 1; off < 32; off <<= 1) {
        p.x += __shfl_xor(p.x, off);
        p.y += __shfl_xor(p.y, off);
        p.z += __shfl_xor(p.z, off);
        p.w += __shfl_xor(p.w, off);
    }
    if (lane == 0) *(float4*)(edO + (size_t)wid * 4) = p;
}

// single relation body (wave per dst node)
template <int CH, typename OT>
__device__ __forceinline__ void agg1_body(
    const int* __restrict__ beg, const int* __restrict__ end_,
    const int* __restrict__ ss, const _Float16* __restrict__ hs,
    const float* __restrict__ es, const float* __restrict__ ed,
    const float* __restrict__ bias, OT* __restrict__ out,
    int relu, const float* __restrict__ wdaO, float* __restrict__ edO,
    int wid, int lane) {
    int h = lane >> 4, el = lane & 15;
    int cl = lane & 31;
    float edh = ed[(size_t)wid * 4 + h];
    float a[4], dn;
    gat_gather<CH>(beg[wid], end_[wid], ss, hs, es, edh, lane, h, el, a, dn);
    float inv = 1.f / (dn + 1e-16f);
    if constexpr (CH == 128) {
        float4 bv = ((const float4*)bias)[cl];
        float o[4];
        o[0] = fmaf(a[0], inv, bv.x); o[1] = fmaf(a[1], inv, bv.y);
        o[2] = fmaf(a[2], inv, bv.z); o[3] = fmaf(a[3], inv, bv.w);
        if (relu) {
#pragma unroll
            for (int i = 0; i < 4; ++i) o[i] = fmaxf(o[i], 0.f);
        }
        if constexpr (sizeof(OT) == 2) {
            h4 ov = {(_Float16)o[0], (_Float16)o[1], (_Float16)o[2], (_Float16)o[3]};
            if (lane < 32) *(h4*)((_Float16*)out + (size_t)wid * 128 + cl * 4) = ov;
#pragma unroll
            for (int i = 0; i < 4; ++i) o[i] = (float)ov[i];
        } else {
            if (lane < 32)
                *(float4*)((float*)out + (size_t)wid * 128 + cl * 4) =
                    make_float4(o[0], o[1], o[2], o[3]);
        }
        if (edO) ed_reduce_write4(o, wdaO, edO, wid, cl, lane);
    } else {
        float o0 = a[0] * inv + bias[cl * 2];
        float o1 = a[1] * inv + bias[cl * 2 + 1];
        if (relu) { o0 = fmaxf(o0, 0.f); o1 = fmaxf(o1, 0.f); }
        if (lane < 32) {
            if constexpr (sizeof(OT) == 2) {
                h2 ov = {(_Float16)o0, (_Float16)o1};
                *(h2*)((_Float16*)out + (size_t)wid * 64 + cl * 2) = ov;
            } else {
                *(float2*)((float*)out + (size_t)wid * 64 + cl * 2) = make_float2(o0, o1);
            }
        }
    }
}

// dual relation body (wave per dst node, summed output)
template <int CH, typename OT>
__device__ __forceinline__ void agg2_body(
    const int* __restrict__ begA, const int* __restrict__ endA,
    const int* __restrict__ ssA, const _Float16* __restrict__ hsA,
    const float* __restrict__ esA, const float* __restrict__ edA,
    const int* __restrict__ begB, const int* __restrict__ endB,
    const int* __restrict__ ssB, const _Float16* __restrict__ hsB,
    const float* __restrict__ esB, const float* __restrict__ edB,
    const float* __restrict__ bsum, OT* __restrict__ out, int relu,
    const float* __restrict__ wda1, float* __restrict__ ed1O,
    const float* __restrict__ wda2, float* __restrict__ ed2O,
    int wid, int lane) {
    int h = lane >> 4, el = lane & 15;
    int cl = lane & 31;
    float edhA = edA[(size_t)wid * 4 + h];
    float edhB = edB[(size_t)wid * 4 + h];
    float aA[4], aB[4], dnA, dnB;
    gat_gather<CH>(begA[wid], endA[wid], ssA, hsA, esA, edhA, lane, h, el, aA, dnA);
    gat_gather<CH>(begB[wid], endB[wid], ssB, hsB, esB, edhB, lane, h, el, aB, dnB);
    float invA = 1.f / (dnA + 1e-16f), invB = 1.f / (dnB + 1e-16f);
    if constexpr (CH == 128) {
        float4 bv = ((const float4*)bsum)[cl];
        float o[4];
        o[0] = fmaf(aA[0], invA, fmaf(aB[0], invB, bv.x));
        o[1] = fmaf(aA[1], invA, fmaf(aB[1], invB, bv.y));
        o[2] = fmaf(aA[2], invA, fmaf(aB[2], invB, bv.z));
        o[3] = fmaf(aA[3], invA, fmaf(aB[3], invB, bv.w));
        if (relu) {
#pragma unroll
            for (int i = 0; i < 4; ++i) o[i] = fmaxf(o[i], 0.f);
        }
        if constexpr (sizeof(OT) == 2) {
            h4 ov = {(_Float16)o[0], (_Float16)o[1], (_Float16)o[2], (_Float16)o[3]};
            if (lane < 32) *(h4*)((_Float16*)out + (size_t)wid * 128 + cl * 4) = ov;
#pragma unroll
            for (int i = 0; i < 4; ++i) o[i] = (float)ov[i];
        } else {
            if (lane < 32)
                *(float4*)((float*)out + (size_t)wid * 128 + cl * 4) =
                    make_float4(o[0], o[1], o[2], o[3]);
        }
        if (ed1O) ed_reduce_write4(o, wda1, ed1O, wid, cl, lane);
        if (ed2O) ed_reduce_write4(o, wda2, ed2O, wid, cl, lane);
    } else {
        float o0 = aA[0] * invA + aB[0] * invB + bsum[cl * 2];
        float o1 = aA[1] * invA + aB[1] * invB + bsum[cl * 2 + 1];
        if (relu) { o0 = fmaxf(o0, 0.f); o1 = fmaxf(o1, 0.f); }
        if (lane < 32) {
            if constexpr (sizeof(OT) == 2) {
                h2 ov = {(_Float16)o0, (_Float16)o1};
                *(h2*)((_Float16*)out + (size_t)wid * 64 + cl * 2) = ov;
            } else {
                *(float2*)((float*)out + (size_t)wid * 64 + cl * 2) = make_float2(o0, o1);
            }
        }
    }
}

// fused per-layer aggregate dispatch: blocks [0,G2) -> dual-relation (paper
// dst); blocks [G2,...) -> single-relation (author dst).
template <int CH, typename OT>
__launch_bounds__(256)
__global__ void agg_fused(
    const int* __restrict__ begA, const int* __restrict__ endA,
    const int* __restrict__ ssA, const _Float16* __restrict__ hsA,
    const float* __restrict__ esA, const float* __restrict__ edA,
    const int* __restrict__ begB, const int* __restrict__ endB,
    const int* __restrict__ ssB, const _Float16* __restrict__ hsB,
    const float* __restrict__ esB, const float* __restrict__ edB,
    const float* __restrict__ bsum, OT* __restrict__ out2, int Ndst2, int relu,
    const float* __restrict__ wda1, float* __restrict__ ed1O,
    const float* __restrict__ wda2, float* __restrict__ ed2O,
    const int* __restrict__ begC, const int* __restrict__ endC,
    const int* __restrict__ ssC, const _Float16* __restrict__ hsC,
    const float* __restrict__ esC, const float* __restrict__ edC,
    const float* __restrict__ biasC, OT* __restrict__ out1, int Ndst1,
    const float* __restrict__ wdaC, float* __restrict__ edCO, int G2) {
    int wave = threadIdx.x >> 6, lane = threadIdx.x & 63;
    int b = blockIdx.x;
    if (b < G2) {
        int wid = b * 4 + wave;
        if (wid >= Ndst2) return;
        agg2_body<CH, OT>(begA, endA, ssA, hsA, esA, edA,
                          begB, endB, ssB, hsB, esB, edB,
                          bsum, out2, relu, wda1, ed1O, wda2, ed2O, wid, lane);
    } else {
        int wid = (b - G2) * 4 + wave;
        if (wid >= Ndst1) return;
        agg1_body<CH, OT>(begC, endC, ssC, hsC, esC, edC, biasC, out1,
                          relu, wdaC, edCO, wid, lane);
    }
}

extern "C" void kernel_launch(void* const* d_in, const int* in_sizes, int n_in,
                              void* d_out, int out_size, void* d_ws, size_t ws_size,
                              hipStream_t stream) {
    const float* xp     = (const float*)d_in[0];
    const float* xa     = (const float*)d_in[1];
    const int* src_pp   = (const int*)d_in[2];
    const int* dst_pp   = (const int*)d_in[3];
    const int* src_ap   = (const int*)d_in[4];
    const int* dst_ap   = (const int*)d_in[5];
    const int* src_pa   = (const int*)d_in[6];
    const int* dst_pa   = (const int*)d_in[7];
    const float* Wsrc1  = (const float*)d_in[8];
    const float* Wdst1  = (const float*)d_in[9];
    const float* asrc1  = (const float*)d_in[10];
    const float* adst1  = (const float*)d_in[11];
    const float* b1     = (const float*)d_in[12];
    const float* Wsrc2  = (const float*)d_in[13];
    const float* Wdst2  = (const float*)d_in[14];
    const float* asrc2  = (const float*)d_in[15];
    const float* adst2  = (const float*)d_in[16];
    const float* b2     = (const float*)d_in[17];

    const int NP  = in_sizes[0] / 128;
    const int NA  = in_sizes[1] / 128;
    const int Epp = in_sizes[2];
    const int Eap = in_sizes[4];
    const int Epa = in_sizes[6];

    const int NB0 = (NP + 127) >> 7, NB1 = (NP + 127) >> 7, NB2 = (NA + 127) >> 7;
    auto cap_of = [](int E, int NB) { int m = E / NB; return ((m * 5 / 4 + 128) + 63) & ~63; };
    const int C0 = cap_of(Epp, NB0), C1 = cap_of(Eap, NB1), C2 = cap_of(Epa, NB2);
    const int c0 = (Epp + ECH - 1) / ECH, c1 = (Eap + ECH - 1) / ECH, c2 = (Epa + ECH - 1) / ECH;

    char* w = (char*)d_ws;
    auto alloc = [&](size_t bytes) {
        char* p = w;
        w += (bytes + 255) & ~(size_t)255;
        return p;
    };
    _Float16* xph = (_Float16*)alloc((size_t)NP * 128 * 2);
    _Float16* xah = (_Float16*)alloc((size_t)NA * 128 * 2);
    _Float16* P1h = (_Float16*)alloc((size_t)NP * 128 * 2);  // rel0 hs (also bt alias)
    _Float16* A1h = (_Float16*)alloc((size_t)NA * 128 * 2);  // rel1 hs
    _Float16* P2h = (_Float16*)alloc((size_t)NP * 128 * 2);  // rel2 hs
    _Float16* HPh = (_Float16*)alloc((size_t)NP * 128 * 2);
    _Float16* HAh = (_Float16*)alloc((size_t)NA * 128 * 2);
    _Float16* Wt  = (_Float16*)alloc((size_t)(3 * 16384 + 3 * 8192) * 2);
    int*   ss0  = (int*)alloc((size_t)NB0 * C0 * 4 + 256);
    int*   ss1  = (int*)alloc((size_t)NB1 * C1 * 4 + 256);
    int*   ss2  = (int*)alloc((size_t)NB2 * C2 * 4 + 256);
    int*   beg0 = (int*)alloc((size_t)NP * 4);
    int*   end0 = (int*)alloc((size_t)NP * 4);
    int*   beg1 = (int*)alloc((size_t)NP * 4);
    int*   end1 = (int*)alloc((size_t)NP * 4);
    int*   beg2 = (int*)alloc((size_t)NA * 4);
    int*   end2 = (int*)alloc((size_t)NA * 4);
    float* ESp  = (float*)alloc((size_t)NP * 4 * 4);
    float* ESa  = (float*)alloc((size_t)NA * 4 * 4);
    float* ESp2 = (float*)alloc((size_t)NP * 4 * 4);
    float* EDpp = (float*)alloc((size_t)NP * 4 * 4);
    float* EDap = (float*)alloc((size_t)NP * 4 * 4);
    float* EDpa = (float*)alloc((size_t)NA * 4 * 4);
    float* WDA  = (float*)alloc(6 * 512 * 4);
    float* BSUM = (float*)alloc(192 * 4);
    int*   bcnt = (int*)alloc((size_t)(NB0 + NB1 + NB2) * 4);
    // bucket staging aliased over P1h (17 MB needed, 25.6 MB available)
    int* bt0 = (int*)P1h;
    int* bt1 = bt0 + (size_t)NB0 * C0;
    int* bt2 = bt1 + (size_t)NB1 * C1;

    const int S = c0 + c1 + c2;
    const int NBtot = NB0 + NB1 + NB2;
    const int CE = (NP + NA + 3) / 4;

    hipMemsetAsync(bcnt, 0, (size_t)NBtot * 4, stream);
    front1<<<S + 13, 256, 0, stream>>>(
        src_pp, dst_pp, Epp, bcnt, bt0, C0, NB0, c0,
        src_ap, dst_ap, Eap, bcnt + NB0, bt1, C1, NB1, c1,
        src_pa, dst_pa, Epa, bcnt + NB0 + NB1, bt2, C2, NB2,
        Wdst1, adst1, Wdst2, adst2, Wsrc1, Wsrc2, b1, b2,
        WDA, Wt, BSUM, S);
    front2<<<NBtot + CE, 256, 0, stream>>>(
        bt0, bcnt, ss0, beg0, end0, NB0, C0, NP,
        bt1, bcnt + NB0, ss1, beg1, end1, NB1, C1, NP,
        bt2, bcnt + NB0 + NB1, ss2, beg2, end2, NB2, C2, NA,
        NBtot,
        xp, xa, NP, NA, xph, xah, WDA, EDpp, EDap, EDpa);

    float* Opap = (float*)d_out;
    float* Oaut = (float*)d_out + (size_t)NP * 64;
    _Float16* Wt1 = Wt;
    _Float16* Wt2 = Wt + 3 * 16384;
    const int TP = (NP + 63) / 64, TA = (NA + 63) / 64;
    const int G2 = (NP + 3) / 4, G1 = (NA + 3) / 4;

    // ---- Layer 1 ----
    gemm3<128><<<TP + TA + TP, 256, 0, stream>>>(
        xph, NP, Wt1, asrc1, P1h, ESp,
        xah, NA, Wt1 + 16384, asrc1 + 128, A1h, ESa,
        xph, NP, Wt1 + 2 * 16384, asrc1 + 2 * 128, P2h, ESp2,
        TP, TP + TA);
    agg_fused<128, _Float16><<<G2 + G1, 256, 0, stream>>>(
        beg0, end0, ss0, P1h, ESp, EDpp,
        beg1, end1, ss1, A1h, ESa, EDap,
        BSUM, HPh, NP, 1, WDA + 3 * 512, EDpp, WDA + 4 * 512, EDap,
        beg2, end2, ss2, P2h, ESp2, EDpa, b1 + 2 * 128, HAh, NA,
        WDA + 5 * 512, EDpa, G2);

    // ---- Layer 2 ----
    gemm3<64><<<TP + TA + TP, 256, 0, stream>>>(
        HPh, NP, Wt2, asrc2, P1h, ESp,
        HAh, NA, Wt2 + 8192, asrc2 + 64, A1h, ESa,
        HPh, NP, Wt2 + 2 * 8192, asrc2 + 2 * 64, P2h, ESp2,
        TP, TP + TA);
    agg_fused<64, float><<<G2 + G1, 256, 0, stream>>>(
        beg0, end0, ss0, P1h, ESp, EDpp,
        beg1, end1, ss1, A1h, ESa, EDap,
        BSUM + 128, Opap, NP, 0, nullptr, nullptr, nullptr, nullptr,
        beg2, end2, ss2, P2h, ESp2, EDpa, b2 + 2 * 64, Oaut, NA,
        nullptr, nullptr, G2);
}

// Round 10
// 613.787 us; speedup vs baseline: 1.0087x; 1.0087x over previous
//
#include <hip/hip_runtime.h>

// ---------------------------------------------------------------------------
// HeteroGAT (2 layers, 3 relations) on MI355X. 6 dispatches/call.
//   front1: bucket_scatter (ECH=4096 chunks) + prep (WDA/Wt/bsum) fused
//   front2: bucket_build + conv_ed (x->fp16 + layer-1 ed GEMVs) fused
//   gemm3:  all 3 relations' hs = X@Wsrc (fp16 MFMA) + fused es, one dispatch
//   agg_fused: per layer, dual-relation (paper dst) + single-relation
//           (author dst) aggregates in ONE dispatch (block-range split).
//   Gather: R8 operating point (best measured): CH=128 R0 layout (2 ch/lane,
//   4-edge-unrolled, readlane s -> SGPR saddr, 0 bank conflicts); CH=64
//   dual-edge halves. Direct-exp softmax + one-block-ahead (s,es) prefetch.
//   This round: inner accumulate via v_fma_mix_f32 (f32 += packed-f16 * f32
//   in ONE VALU op) — halves the cvt+fma pair that was layout-invariant
//   across R0-R9 (~105us VALU floor). R9's dual-edge CH=128 reverted
//   (183us, +4M bank conflicts from bpermute vs readlane).
// ---------------------------------------------------------------------------

#define LEAKY(x) ((x) > 0.f ? (x) : 0.2f * (x))
#define ECH 4096
#define NBMAX 784

typedef _Float16 h8 __attribute__((ext_vector_type(8)));
typedef _Float16 h2 __attribute__((ext_vector_type(2)));
typedef float f4 __attribute__((ext_vector_type(4)));

// acc0 += lo16(pk) * w; acc1 += hi16(pk) * w   (one VALU op each)
__device__ __forceinline__ void fmix2(float& a0, float& a1, unsigned pk, float w) {
    asm("v_fma_mix_f32 %0, %2, %3, %0 op_sel:[0,0,0] op_sel_hi:[1,0,0]\n\t"
        "v_fma_mix_f32 %1, %2, %3, %1 op_sel:[1,0,0] op_sel_hi:[1,0,0]"
        : "+v"(a0), "+v"(a1)
        : "v"(pk), "v"(w));
}

// ---------------- front1: bucket_scatter chunks + prep ----------------
__launch_bounds__(256)
__global__ void front1(
    const int* __restrict__ s0, const int* __restrict__ d0, int E0,
    int* __restrict__ bc0, int* __restrict__ bt0, int C0, int NB0, int c0,
    const int* __restrict__ s1, const int* __restrict__ d1, int E1,
    int* __restrict__ bc1, int* __restrict__ bt1, int C1, int NB1, int c1,
    const int* __restrict__ s2, const int* __restrict__ d2, int E2,
    int* __restrict__ bc2, int* __restrict__ bt2, int C2, int NB2,
    const float* __restrict__ Wdst1, const float* __restrict__ adst1,
    const float* __restrict__ Wdst2, const float* __restrict__ adst2,
    const float* __restrict__ Wsrc1, const float* __restrict__ Wsrc2,
    const float* __restrict__ b1, const float* __restrict__ b2,
    float* __restrict__ WDA, _Float16* __restrict__ Wt,
    float* __restrict__ bsum, int S) {
    __shared__ int lcnt[NBMAX], lbase[NBMAX];
    int blk = blockIdx.x;
    int t = threadIdx.x;
    if (blk < S) {
        int ch = blk;
        const int* src; const int* dst; int* bc; int* bt; int cap, NB, E;
        if (ch < c0)            { src = s0; dst = d0; bc = bc0; bt = bt0; cap = C0; NB = NB0; E = E0; }
        else if (ch < c0 + c1)  { ch -= c0; src = s1; dst = d1; bc = bc1; bt = bt1; cap = C1; NB = NB1; E = E1; }
        else                    { ch -= c0 + c1; src = s2; dst = d2; bc = bc2; bt = bt2; cap = C2; NB = NB2; E = E2; }
        int ebeg = ch * ECH;
        int eend = ebeg + ECH < E ? ebeg + ECH : E;

        for (int b = t; b < NB; b += 256) lcnt[b] = 0;
        __syncthreads();
        for (int i = ebeg + t; i < eend; i += 256) atomicAdd(&lcnt[dst[i] >> 7], 1);
        __syncthreads();
        for (int b = t; b < NB; b += 256) {
            int c = lcnt[b];
            lbase[b] = c ? atomicAdd(&bc[b], c) : 0;
            lcnt[b] = 0;
        }
        __syncthreads();
        for (int i = ebeg + t; i < eend; i += 256) {
            int d = dst[i], b = d >> 7;
            int p = lbase[b] + atomicAdd(&lcnt[b], 1);
            if (p < cap) bt[(size_t)b * cap + p] = src[i] | ((d & 127) << 20);
        }
    } else {
        int r = blk - S;
        if (r < 6) {
            const float* Wd; const float* ad; int Ncol, C;
            if (r < 3) { Wd = Wdst1 + r * 16384; ad = adst1 + r * 128; Ncol = 128; C = 32; }
            else       { Wd = Wdst2 + (r - 3) * 8192; ad = adst2 + (r - 3) * 64; Ncol = 64; C = 16; }
            for (int tt = t; tt < 512; tt += 256) {
                int f = tt >> 2, h = tt & 3;
                float s = 0.f;
                for (int c = 0; c < C; ++c) s += Wd[f * Ncol + h * C + c] * ad[h * C + c];
                WDA[r * 512 + f * 4 + h] = s;
            }
        } else if (r < 12) {
            int rr = r - 6;
            const float* W; _Float16* o; int BN;
            if (rr < 3) { W = Wsrc1 + rr * 16384; o = Wt + rr * 16384; BN = 128; }
            else        { W = Wsrc2 + (rr - 3) * 8192; o = Wt + 3 * 16384 + (rr - 3) * 8192; BN = 64; }
            for (int idx = t; idx < BN * 128; idx += 256) {
                int n = idx >> 7, k = idx & 127;
                o[idx] = (_Float16)W[k * BN + n];
            }
        } else {
            if (t < 128) bsum[t] = b1[t] + b1[128 + t];
            else if (t < 192) bsum[128 + (t - 128)] = b2[t - 128] + b2[64 + (t - 128)];
        }
    }
}

// ---------------- front2: bucket_build + conv_ed ----------------
__launch_bounds__(256)
__global__ void front2(
    const int* __restrict__ bt0, const int* __restrict__ bc0, int* __restrict__ ss0,
    int* __restrict__ beg0, int* __restrict__ end0, int NB0, int C0, int Nd0,
    const int* __restrict__ bt1, const int* __restrict__ bc1, int* __restrict__ ss1,
    int* __restrict__ beg1, int* __restrict__ end1, int NB1, int C1, int Nd1,
    const int* __restrict__ bt2, const int* __restrict__ bc2, int* __restrict__ ss2,
    int* __restrict__ beg2, int* __restrict__ end2, int NB2, int C2, int Nd2,
    int NBtot,
    const float* __restrict__ xp, const float* __restrict__ xa,
    int NP, int NA, _Float16* __restrict__ xph, _Float16* __restrict__ xah,
    const float* __restrict__ WDA,
    float* __restrict__ EDpp, float* __restrict__ EDap, float* __restrict__ EDpa) {
    __shared__ int hist[128], pre[129], cur[128];
    int blk = blockIdx.x;
    int tid = threadIdx.x;
    if (blk < NBtot) {
        int bb = blk;
        const int* bt; const int* bcp; int* ssp; int* bg; int* en; int cap, nd;
        if (bb < NB0)            { bt = bt0; bcp = bc0; ssp = ss0; bg = beg0; en = end0; cap = C0; nd = Nd0; }
        else if (bb < NB0 + NB1) { bb -= NB0; bt = bt1; bcp = bc1; ssp = ss1; bg = beg1; en = end1; cap = C1; nd = Nd1; }
        else                     { bb -= NB0 + NB1; bt = bt2; bcp = bc2; ssp = ss2; bg = beg2; en = end2; cap = C2; nd = Nd2; }
        int n = bcp[bb]; if (n > cap) n = cap;
        const int* btb = bt + (size_t)bb * cap;
        int ssbase = bb * cap;
        int dbase = bb << 7;

        if (tid < 128) hist[tid] = 0;
        __syncthreads();
        for (int i = tid; i < n; i += 256) atomicAdd(&hist[btb[i] >> 20], 1);
        __syncthreads();
        if (tid < 128) pre[tid + 1] = hist[tid];
        if (tid == 0) pre[0] = 0;
        __syncthreads();
        for (int off = 1; off < 128; off <<= 1) {
            int v = 0;
            if (tid < 128) {
                int i = tid + 1;
                v = pre[i] + ((i > off) ? pre[i - off] : 0);
            }
            __syncthreads();
            if (tid < 128) pre[tid + 1] = v;
            __syncthreads();
        }
        if (tid < 128) {
            int d = dbase + tid;
            if (d < nd) {
                int b_ = ssbase + pre[tid];
                bg[d] = b_;
                en[d] = b_ + hist[tid];
            }
            cur[tid] = 0;
        }
        __syncthreads();
        for (int i = tid; i < n; i += 256) {
            int v = btb[i];
            int dl = v >> 20;
            int p = atomicAdd(&cur[dl], 1);
            ssp[ssbase + pre[dl] + p] = v & 0xFFFFF;
        }
    } else {
        int wid = (blk - NBtot) * 4 + (tid >> 6);
        if (wid >= NP + NA) return;
        int lane = tid & 63;
        const float* x; _Float16* xh; const float4* W0; const float4* W1;
        float* e0p; float* e1p; int row;
        if (wid < NP) { row = wid; x = xp; xh = xph; W0 = (const float4*)WDA;
                        W1 = (const float4*)(WDA + 512); e0p = EDpp; e1p = EDap; }
        else { row = wid - NP; x = xa; xh = xah; W0 = (const float4*)(WDA + 1024);
               W1 = nullptr; e0p = EDpa; e1p = nullptr; }
        float2 xv = *(const float2*)(x + (size_t)row * 128 + lane * 2);
        h2 hv = {(_Float16)xv.x, (_Float16)xv.y};
        *(h2*)(xh + (size_t)row * 128 + lane * 2) = hv;
        float4 a0 = W0[lane * 2], a1 = W0[lane * 2 + 1];
        float4 p = make_float4(xv.x * a0.x + xv.y * a1.x, xv.x * a0.y + xv.y * a1.y,
                               xv.x * a0.z + xv.y * a1.z, xv.x * a0.w + xv.y * a1.w);
        float4 q = make_float4(0.f, 0.f, 0.f, 0.f);
        if (W1) {
            float4 b0 = W1[lane * 2], b1 = W1[lane * 2 + 1];
            q = make_float4(xv.x * b0.x + xv.y * b1.x, xv.x * b0.y + xv.y * b1.y,
                            xv.x * b0.z + xv.y * b1.z, xv.x * b0.w + xv.y * b1.w);
        }
#pragma unroll
        for (int off = 32; off; off >>= 1) {
            p.x += __shfl_xor(p.x, off); p.y += __shfl_xor(p.y, off);
            p.z += __shfl_xor(p.z, off); p.w += __shfl_xor(p.w, off);
            q.x += __shfl_xor(q.x, off); q.y += __shfl_xor(q.y, off);
            q.z += __shfl_xor(q.z, off); q.w += __shfl_xor(q.w, off);
        }
        if (lane == 0) {
            *(float4*)(e0p + (size_t)row * 4) = p;
            if (e1p) *(float4*)(e1p + (size_t)row * 4) = q;
        }
    }
}

// ---------------- fp16 MFMA GEMM x3 relations + fused es ----------------
template <int BN>
__launch_bounds__(256)
__global__ void gemm3(const _Float16* __restrict__ A0, int M0, const _Float16* __restrict__ W0,
                      const float* __restrict__ as0, _Float16* __restrict__ O0, float* __restrict__ es0,
                      const _Float16* __restrict__ A1, int M1, const _Float16* __restrict__ W1,
                      const float* __restrict__ as1, _Float16* __restrict__ O1, float* __restrict__ es1,
                      const _Float16* __restrict__ A2, int M2, const _Float16* __restrict__ W2,
                      const float* __restrict__ as2, _Float16* __restrict__ O2, float* __restrict__ es2,
                      int t0, int t1) {
    constexpr int NT = BN / 16;
    constexpr int LDA = 136;
    __shared__ _Float16 As[64 * LDA];
    __shared__ _Float16 Ws[BN * LDA];
    int b = blockIdx.x;
    const _Float16* A; const _Float16* Wt; const float* a_s; _Float16* Chs; float* es;
    int M, tile;
    if (b < t0)      { A = A0; M = M0; Wt = W0; a_s = as0; Chs = O0; es = es0; tile = b; }
    else if (b < t1) { A = A1; M = M1; Wt = W1; a_s = as1; Chs = O1; es = es1; tile = b - t0; }
    else             { A = A2; M = M2; Wt = W2; a_s = as2; Chs = O2; es = es2; tile = b - t1; }
    const int tid = threadIdx.x;
    const int wave = tid >> 6, lane = tid & 63;
    const int l15 = lane & 15, quad = lane >> 4;
    const int row0 = tile * 64;
    const int maxr = M - row0;

#pragma unroll
    for (int c = 0; c < 4; ++c) {
        int idx = c * 256 + tid;
        int row = idx >> 4, off = (idx & 15) * 8;
        h8 v = {};
        if (row < maxr) v = *(const h8*)(A + (size_t)(row0 + row) * 128 + off);
        *(h8*)(As + row * LDA + off) = v;
    }
#pragma unroll
    for (int c = 0; c < NT; ++c) {
        int idx = c * 256 + tid;
        int row = idx >> 4, off = (idx & 15) * 8;
        *(h8*)(Ws + row * LDA + off) = *(const h8*)(Wt + (size_t)row * 128 + off);
    }
    __syncthreads();

    f4 acc[NT];
#pragma unroll
    for (int nt = 0; nt < NT; ++nt) acc[nt] = {0.f, 0.f, 0.f, 0.f};

    const _Float16* ap = As + (wave * 16 + l15) * LDA + quad * 8;
#pragma unroll
    for (int k0 = 0; k0 < 128; k0 += 32) {
        h8 a = *(const h8*)(ap + k0);
#pragma unroll
        for (int nt = 0; nt < NT; ++nt) {
            h8 bb = *(const h8*)(Ws + (nt * 16 + l15) * LDA + k0 + quad * 8);
            acc[nt] = __builtin_amdgcn_mfma_f32_16x16x32_f16(a, bb, acc[nt], 0, 0, 0);
        }
    }

    float av[NT];
#pragma unroll
    for (int nt = 0; nt < NT; ++nt) av[nt] = a_s[nt * 16 + l15];
    constexpr int TPH = NT / 4;
#pragma unroll
    for (int r = 0; r < 4; ++r) {
        int row = wave * 16 + quad * 4 + r;
        bool ok = row < maxr;
        if (ok) {
            _Float16* outp = Chs + (size_t)(row0 + row) * BN + l15;
#pragma unroll
            for (int nt = 0; nt < NT; ++nt) outp[nt * 16] = (_Float16)acc[nt][r];
        }
        float p0 = 0.f, p1 = 0.f, p2 = 0.f, p3 = 0.f;
#pragma unroll
        for (int i = 0; i < TPH; ++i) {
            p0 += acc[0 * TPH + i][r] * av[0 * TPH + i];
            p1 += acc[1 * TPH + i][r] * av[1 * TPH + i];
            p2 += acc[2 * TPH + i][r] * av[2 * TPH + i];
            p3 += acc[3 * TPH + i][r] * av[3 * TPH + i];
        }
#pragma unroll
        for (int off = 1; off < 16; off <<= 1) {
            p0 += __shfl_xor(p0, off);
            p1 += __shfl_xor(p1, off);
            p2 += __shfl_xor(p2, off);
            p3 += __shfl_xor(p3, off);
        }
        if (ok && l15 < 4) {
            float pv = (l15 == 0) ? p0 : (l15 == 1) ? p1 : (l15 == 2) ? p2 : p3;
            es[(size_t)(row0 + row) * 4 + l15] = pv;
        }
    }
}

// ---------------- aggregation ----------------
// Direct-exp softmax; (s,es) prefetched one 16-edge block ahead.
// CH=128: lane owns channels (2*lane, 2*lane+1); 4-edge-unrolled j-loop,
//   readlane s -> SGPR base (saddr loads); packed-dword + v_fma_mix accum.
// CH=64: dual-edge halves; cl=lane&31 owns channels (2cl,2cl+1) of edge
//   j+(lane>>5); 8-edge-batched steps; final xor-32 merge; fma_mix accum.
template <int CH>
__device__ __forceinline__ void gat_gather(
    int b0, int e0, const int* __restrict__ ss, const _Float16* __restrict__ hs,
    const float* __restrict__ es, float edh, int lane, int h, int el,
    float& racc0, float& racc1, float& rden) {
    const char* hsb = (const char*)hs;
    const char* esb = (const char*)es;
    float acc0 = 0.f, acc1 = 0.f, den = 0.f;
    if constexpr (CH == 128) {
        const unsigned lb = (unsigned)(lane * 4);
        int n = e0 - b0; if (n > 16) n = 16; if (n < 0) n = 0;
        int s = 0; float eraw = 0.f;
        if (el < n) {
            s = ss[b0 + el];
            eraw = *(const float*)(esb + ((unsigned)s * 16u + (unsigned)(h * 4)));
        }
        for (int base = b0; base < e0; base += 16) {
            // prefetch next block's s/eraw (predicated off past the end)
            int n2 = e0 - (base + 16); if (n2 > 16) n2 = 16;
            int s2 = 0; float eraw2 = 0.f;
            if (el < n2) {
                s2 = ss[base + 16 + el];
                eraw2 = *(const float*)(esb + ((unsigned)s2 * 16u + (unsigned)(h * 4)));
            }
            float w = 0.f;
            if (el < n) {
                float e = eraw + edh;
                e = LEAKY(e);
                w = __expf(e);
            }
            int j = 0;
            for (; j + 4 <= n; j += 4) {
                int sa = __builtin_amdgcn_readlane(s, j);
                int sb = __builtin_amdgcn_readlane(s, j + 1);
                int sc = __builtin_amdgcn_readlane(s, j + 2);
                int sd = __builtin_amdgcn_readlane(s, j + 3);
                float w0 = __shfl(w, (h << 4) | j);
                float w1 = __shfl(w, (h << 4) | (j + 1));
                float w2 = __shfl(w, (h << 4) | (j + 2));
                float w3 = __shfl(w, (h << 4) | (j + 3));
                unsigned q0 = *(const unsigned*)(hsb + ((unsigned)sa * 256u + lb));
                unsigned q1 = *(const unsigned*)(hsb + ((unsigned)sb * 256u + lb));
                unsigned q2 = *(const unsigned*)(hsb + ((unsigned)sc * 256u + lb));
                unsigned q3 = *(const unsigned*)(hsb + ((unsigned)sd * 256u + lb));
                fmix2(acc0, acc1, q0, w0);
                fmix2(acc0, acc1, q1, w1);
                fmix2(acc0, acc1, q2, w2);
                fmix2(acc0, acc1, q3, w3);
                den += w0 + w1 + w2 + w3;
            }
            for (; j < n; ++j) {
                int sj = __builtin_amdgcn_readlane(s, j);
                float wj = __shfl(w, (h << 4) | j);
                unsigned qj = *(const unsigned*)(hsb + ((unsigned)sj * 256u + lb));
                fmix2(acc0, acc1, qj, wj);
                den += wj;
            }
            s = s2; eraw = eraw2; n = n2;
        }
    } else {
        const int half = lane >> 5;        // which edge of the dual pair
        const int cl = lane & 31;          // channel-pair index
        const int hh = cl >> 3;            // head of channels 2cl,2cl+1
        const unsigned lb = (unsigned)(cl * 4);
        int n = e0 - b0; if (n > 16) n = 16; if (n < 0) n = 0;
        int s = 0; float eraw = 0.f;
        if (el < n) {
            s = ss[b0 + el];
            eraw = *(const float*)(esb + ((unsigned)s * 16u + (unsigned)(h * 4)));
        }
        for (int base = b0; base < e0; base += 16) {
            int n2 = e0 - (base + 16); if (n2 > 16) n2 = 16;
            int sp = 0; float erawp = 0.f;
            if (el < n2) {
                sp = ss[base + 16 + el];
                erawp = *(const float*)(esb + ((unsigned)sp * 16u + (unsigned)(h * 4)));
            }
            float w = 0.f;
            if (el < n) {
                float e = eraw + edh;
                e = LEAKY(e);
                w = __expf(e);
            }
            // edges beyond n carry s=0, w=0 -> padded slots are harmless.
            for (int j = 0; j < n; j += 8) {
                int t0 = __shfl(s, j + half);
                int t1 = __shfl(s, j + 2 + half);
                int t2 = __shfl(s, j + 4 + half);
                int t3 = __shfl(s, j + 6 + half);
                float w0 = __shfl(w, (hh << 4) | (j + half));
                float w1 = __shfl(w, (hh << 4) | (j + 2 + half));
                float w2 = __shfl(w, (hh << 4) | (j + 4 + half));
                float w3 = __shfl(w, (hh << 4) | (j + 6 + half));
                unsigned q0 = *(const unsigned*)(hsb + ((unsigned)t0 * 128u + lb));
                unsigned q1 = *(const unsigned*)(hsb + ((unsigned)t1 * 128u + lb));
                unsigned q2 = *(const unsigned*)(hsb + ((unsigned)t2 * 128u + lb));
                unsigned q3 = *(const unsigned*)(hsb + ((unsigned)t3 * 128u + lb));
                fmix2(acc0, acc1, q0, w0);
                fmix2(acc0, acc1, q1, w1);
                fmix2(acc0, acc1, q2, w2);
                fmix2(acc0, acc1, q3, w3);
                den += w0 + w1 + w2 + w3;
            }
            s = sp; eraw = erawp; n = n2;
        }
        // merge the two halves (disjoint edge subsets, same channel pair)
        acc0 += __shfl_xor(acc0, 32);
        acc1 += __shfl_xor(acc1, 32);
        den += __shfl_xor(den, 32);
    }
    racc0 = acc0; racc1 = acc1; rden = den;
}

__device__ __forceinline__ void ed_reduce_write(float o0, float o1, const float* wda,
                                                float* edO, int wid, int lane) {
    const float4* W = (const float4*)wda;
    float4 w0 = W[lane * 2], w1 = W[lane * 2 + 1];
    float4 p = make_float4(o0 * w0.x + o1 * w1.x, o0 * w0.y + o1 * w1.y,
                           o0 * w0.z + o1 * w1.z, o0 * w0.w + o1 * w1.w);
#pragma unroll
    for (int off = 32; off; off >>= 1) {
        p.x += __shfl_xor(p.x, off); p.y += __shfl_xor(p.y, off);
        p.z += __shfl_xor(p.z, off); p.w += __shfl_xor(p.w, off);
    }
    if (lane == 0) *(float4*)(edO + (size_t)wid * 4) = p;
}

// single relation body (wave per dst node)
template <int CH, typename OT>
__device__ __forceinline__ void agg1_body(
    const int* __restrict__ beg, const int* __restrict__ end_,
    const int* __restrict__ ss, const _Float16* __restrict__ hs,
    const float* __restrict__ es, const float* __restrict__ ed,
    const float* __restrict__ bias, OT* __restrict__ out,
    int relu, const float* __restrict__ wdaO, float* __restrict__ edO,
    int wid, int lane) {
    int h = lane >> 4, el = lane & 15;
    float edh = ed[(size_t)wid * 4 + h];
    float a0, a1, dn;
    gat_gather<CH>(beg[wid], end_[wid], ss, hs, es, edh, lane, h, el, a0, a1, dn);
    float inv = 1.f / (dn + 1e-16f);
    if constexpr (CH == 128) {
        float o0 = a0 * inv + bias[lane * 2];
        float o1 = a1 * inv + bias[lane * 2 + 1];
        if (relu) { o0 = fmaxf(o0, 0.f); o1 = fmaxf(o1, 0.f); }
        size_t i0 = (size_t)wid * 128 + lane * 2;
        if constexpr (sizeof(OT) == 2) {
            h2 ov = {(_Float16)o0, (_Float16)o1};
            *(h2*)((_Float16*)out + i0) = ov;
            o0 = (float)ov[0]; o1 = (float)ov[1];
        } else {
            *(float2*)((float*)out + i0) = make_float2(o0, o1);
        }
        if (edO) ed_reduce_write(o0, o1, wdaO, edO, wid, lane);
    } else {
        int cl = lane & 31;
        float o0 = a0 * inv + bias[cl * 2];
        float o1 = a1 * inv + bias[cl * 2 + 1];
        if (relu) { o0 = fmaxf(o0, 0.f); o1 = fmaxf(o1, 0.f); }
        if (lane < 32) {
            if constexpr (sizeof(OT) == 2) {
                h2 ov = {(_Float16)o0, (_Float16)o1};
                *(h2*)((_Float16*)out + (size_t)wid * 64 + cl * 2) = ov;
            } else {
                *(float2*)((float*)out + (size_t)wid * 64 + cl * 2) = make_float2(o0, o1);
            }
        }
    }
}

// dual relation body (wave per dst node, summed output)
template <int CH, typename OT>
__device__ __forceinline__ void agg2_body(
    const int* __restrict__ begA, const int* __restrict__ endA,
    const int* __restrict__ ssA, const _Float16* __restrict__ hsA,
    const float* __restrict__ esA, const float* __restrict__ edA,
    const int* __restrict__ begB, const int* __restrict__ endB,
    const int* __restrict__ ssB, const _Float16* __restrict__ hsB,
    const float* __restrict__ esB, const float* __restrict__ edB,
    const float* __restrict__ bsum, OT* __restrict__ out, int relu,
    const float* __restrict__ wda1, float* __restrict__ ed1O,
    const float* __restrict__ wda2, float* __restrict__ ed2O,
    int wid, int lane) {
    int h = lane >> 4, el = lane & 15;
    float edhA = edA[(size_t)wid * 4 + h];
    float edhB = edB[(size_t)wid * 4 + h];
    float aA0, aA1, dnA, aB0, aB1, dnB;
    gat_gather<CH>(begA[wid], endA[wid], ssA, hsA, esA, edhA, lane, h, el, aA0, aA1, dnA);
    gat_gather<CH>(begB[wid], endB[wid], ssB, hsB, esB, edhB, lane, h, el, aB0, aB1, dnB);
    float invA = 1.f / (dnA + 1e-16f), invB = 1.f / (dnB + 1e-16f);
    if constexpr (CH == 128) {
        float o0 = aA0 * invA + aB0 * invB + bsum[lane * 2];
        float o1 = aA1 * invA + aB1 * invB + bsum[lane * 2 + 1];
        if (relu) { o0 = fmaxf(o0, 0.f); o1 = fmaxf(o1, 0.f); }
        size_t i0 = (size_t)wid * 128 + lane * 2;
        if constexpr (sizeof(OT) == 2) {
            h2 ov = {(_Float16)o0, (_Float16)o1};
            *(h2*)((_Float16*)out + i0) = ov;
            o0 = (float)ov[0]; o1 = (float)ov[1];
        } else {
            *(float2*)((float*)out + i0) = make_float2(o0, o1);
        }
        if (ed1O) ed_reduce_write(o0, o1, wda1, ed1O, wid, lane);
        if (ed2O) ed_reduce_write(o0, o1, wda2, ed2O, wid, lane);
    } else {
        int cl = lane & 31;
        float o0 = aA0 * invA + aB0 * invB + bsum[cl * 2];
        float o1 = aA1 * invA + aB1 * invB + bsum[cl * 2 + 1];
        if (relu) { o0 = fmaxf(o0, 0.f); o1 = fmaxf(o1, 0.f); }
        if (lane < 32) {
            if constexpr (sizeof(OT) == 2) {
                h2 ov = {(_Float16)o0, (_Float16)o1};
                *(h2*)((_Float16*)out + (size_t)wid * 64 + cl * 2) = ov;
            } else {
                *(float2*)((float*)out + (size_t)wid * 64 + cl * 2) = make_float2(o0, o1);
            }
        }
    }
}

// fused per-layer aggregate dispatch: blocks [0,G2) -> dual-relation (paper
// dst); blocks [G2,...) -> single-relation (author dst).
template <int CH, typename OT>
__launch_bounds__(256)
__global__ void agg_fused(
    const int* __restrict__ begA, const int* __restrict__ endA,
    const int* __restrict__ ssA, const _Float16* __restrict__ hsA,
    const float* __restrict__ esA, const float* __restrict__ edA,
    const int* __restrict__ begB, const int* __restrict__ endB,
    const int* __restrict__ ssB, const _Float16* __restrict__ hsB,
    const float* __restrict__ esB, const float* __restrict__ edB,
    const float* __restrict__ bsum, OT* __restrict__ out2, int Ndst2, int relu,
    const float* __restrict__ wda1, float* __restrict__ ed1O,
    const float* __restrict__ wda2, float* __restrict__ ed2O,
    const int* __restrict__ begC, const int* __restrict__ endC,
    const int* __restrict__ ssC, const _Float16* __restrict__ hsC,
    const float* __restrict__ esC, const float* __restrict__ edC,
    const float* __restrict__ biasC, OT* __restrict__ out1, int Ndst1,
    const float* __restrict__ wdaC, float* __restrict__ edCO, int G2) {
    int wave = threadIdx.x >> 6, lane = threadIdx.x & 63;
    int b = blockIdx.x;
    if (b < G2) {
        int wid = b * 4 + wave;
        if (wid >= Ndst2) return;
        agg2_body<CH, OT>(begA, endA, ssA, hsA, esA, edA,
                          begB, endB, ssB, hsB, esB, edB,
                          bsum, out2, relu, wda1, ed1O, wda2, ed2O, wid, lane);
    } else {
        int wid = (b - G2) * 4 + wave;
        if (wid >= Ndst1) return;
        agg1_body<CH, OT>(begC, endC, ssC, hsC, esC, edC, biasC, out1,
                          relu, wdaC, edCO, wid, lane);
    }
}

extern "C" void kernel_launch(void* const* d_in, const int* in_sizes, int n_in,
                              void* d_out, int out_size, void* d_ws, size_t ws_size,
                              hipStream_t stream) {
    const float* xp     = (const float*)d_in[0];
    const float* xa     = (const float*)d_in[1];
    const int* src_pp   = (const int*)d_in[2];
    const int* dst_pp   = (const int*)d_in[3];
    const int* src_ap   = (const int*)d_in[4];
    const int* dst_ap   = (const int*)d_in[5];
    const int* src_pa   = (const int*)d_in[6];
    const int* dst_pa   = (const int*)d_in[7];
    const float* Wsrc1  = (const float*)d_in[8];
    const float* Wdst1  = (const float*)d_in[9];
    const float* asrc1  = (const float*)d_in[10];
    const float* adst1  = (const float*)d_in[11];
    const float* b1     = (const float*)d_in[12];
    const float* Wsrc2  = (const float*)d_in[13];
    const float* Wdst2  = (const float*)d_in[14];
    const float* asrc2  = (const float*)d_in[15];
    const float* adst2  = (const float*)d_in[16];
    const float* b2     = (const float*)d_in[17];

    const int NP  = in_sizes[0] / 128;
    const int NA  = in_sizes[1] / 128;
    const int Epp = in_sizes[2];
    const int Eap = in_sizes[4];
    const int Epa = in_sizes[6];

    const int NB0 = (NP + 127) >> 7, NB1 = (NP + 127) >> 7, NB2 = (NA + 127) >> 7;
    auto cap_of = [](int E, int NB) { int m = E / NB; return ((m * 5 / 4 + 128) + 63) & ~63; };
    const int C0 = cap_of(Epp, NB0), C1 = cap_of(Eap, NB1), C2 = cap_of(Epa, NB2);
    const int c0 = (Epp + ECH - 1) / ECH, c1 = (Eap + ECH - 1) / ECH, c2 = (Epa + ECH - 1) / ECH;

    char* w = (char*)d_ws;
    auto alloc = [&](size_t bytes) {
        char* p = w;
        w += (bytes + 255) & ~(size_t)255;
        return p;
    };
    _Float16* xph = (_Float16*)alloc((size_t)NP * 128 * 2);
    _Float16* xah = (_Float16*)alloc((size_t)NA * 128 * 2);
    _Float16* P1h = (_Float16*)alloc((size_t)NP * 128 * 2);  // rel0 hs (also bt alias)
    _Float16* A1h = (_Float16*)alloc((size_t)NA * 128 * 2);  // rel1 hs
    _Float16* P2h = (_Float16*)alloc((size_t)NP * 128 * 2);  // rel2 hs
    _Float16* HPh = (_Float16*)alloc((size_t)NP * 128 * 2);
    _Float16* HAh = (_Float16*)alloc((size_t)NA * 128 * 2);
    _Float16* Wt  = (_Float16*)alloc((size_t)(3 * 16384 + 3 * 8192) * 2);
    int*   ss0  = (int*)alloc((size_t)NB0 * C0 * 4 + 256);
    int*   ss1  = (int*)alloc((size_t)NB1 * C1 * 4 + 256);
    int*   ss2  = (int*)alloc((size_t)NB2 * C2 * 4 + 256);
    int*   beg0 = (int*)alloc((size_t)NP * 4);
    int*   end0 = (int*)alloc((size_t)NP * 4);
    int*   beg1 = (int*)alloc((size_t)NP * 4);
    int*   end1 = (int*)alloc((size_t)NP * 4);
    int*   beg2 = (int*)alloc((size_t)NA * 4);
    int*   end2 = (int*)alloc((size_t)NA * 4);
    float* ESp  = (float*)alloc((size_t)NP * 4 * 4);
    float* ESa  = (float*)alloc((size_t)NA * 4 * 4);
    float* ESp2 = (float*)alloc((size_t)NP * 4 * 4);
    float* EDpp = (float*)alloc((size_t)NP * 4 * 4);
    float* EDap = (float*)alloc((size_t)NP * 4 * 4);
    float* EDpa = (float*)alloc((size_t)NA * 4 * 4);
    float* WDA  = (float*)alloc(6 * 512 * 4);
    float* BSUM = (float*)alloc(192 * 4);
    int*   bcnt = (int*)alloc((size_t)(NB0 + NB1 + NB2) * 4);
    // bucket staging aliased over P1h (17 MB needed, 25.6 MB available)
    int* bt0 = (int*)P1h;
    int* bt1 = bt0 + (size_t)NB0 * C0;
    int* bt2 = bt1 + (size_t)NB1 * C1;

    const int S = c0 + c1 + c2;
    const int NBtot = NB0 + NB1 + NB2;
    const int CE = (NP + NA + 3) / 4;

    hipMemsetAsync(bcnt, 0, (size_t)NBtot * 4, stream);
    front1<<<S + 13, 256, 0, stream>>>(
        src_pp, dst_pp, Epp, bcnt, bt0, C0, NB0, c0,
        src_ap, dst_ap, Eap, bcnt + NB0, bt1, C1, NB1, c1,
        src_pa, dst_pa, Epa, bcnt + NB0 + NB1, bt2, C2, NB2,
        Wdst1, adst1, Wdst2, adst2, Wsrc1, Wsrc2, b1, b2,
        WDA, Wt, BSUM, S);
    front2<<<NBtot + CE, 256, 0, stream>>>(
        bt0, bcnt, ss0, beg0, end0, NB0, C0, NP,
        bt1, bcnt + NB0, ss1, beg1, end1, NB1, C1, NP,
        bt2, bcnt + NB0 + NB1, ss2, beg2, end2, NB2, C2, NA,
        NBtot,
        xp, xa, NP, NA, xph, xah, WDA, EDpp, EDap, EDpa);

    float* Opap = (float*)d_out;
    float* Oaut = (float*)d_out + (size_t)NP * 64;
    _Float16* Wt1 = Wt;
    _Float16* Wt2 = Wt + 3 * 16384;
    const int TP = (NP + 63) / 64, TA = (NA + 63) / 64;
    const int G2 = (NP + 3) / 4, G1 = (NA + 3) / 4;

    // ---- Layer 1 ----
    gemm3<128><<<TP + TA + TP, 256, 0, stream>>>(
        xph, NP, Wt1, asrc1, P1h, ESp,
        xah, NA, Wt1 + 16384, asrc1 + 128, A1h, ESa,
        xph, NP, Wt1 + 2 * 16384, asrc1 + 2 * 128, P2h, ESp2,
        TP, TP + TA);
    agg_fused<128, _Float16><<<G2 + G1, 256, 0, stream>>>(
        beg0, end0, ss0, P1h, ESp, EDpp,
        beg1, end1, ss1, A1h, ESa, EDap,
        BSUM, HPh, NP, 1, WDA + 3 * 512, EDpp, WDA + 4 * 512, EDap,
        beg2, end2, ss2, P2h, ESp2, EDpa, b1 + 2 * 128, HAh, NA,
        WDA + 5 * 512, EDpa, G2);

    // ---- Layer 2 ----
    gemm3<64><<<TP + TA + TP, 256, 0, stream>>>(
        HPh, NP, Wt2, asrc2, P1h, ESp,
        HAh, NA, Wt2 + 8192, asrc2 + 64, A1h, ESa,
        HPh, NP, Wt2 + 2 * 8192, asrc2 + 2 * 64, P2h, ESp2,
        TP, TP + TA);
    agg_fused<64, float><<<G2 + G1, 256, 0, stream>>>(
        beg0, end0, ss0, P1h, ESp, EDpp,
        beg1, end1, ss1, A1h, ESa, EDap,
        BSUM + 128, Opap, NP, 0, nullptr, nullptr, nullptr, nullptr,
        beg2, end2, ss2, P2h, ESp2, EDpa, b2 + 2 * 64, Oaut, NA,
        nullptr, nullptr, G2);
}